// Round 1
// baseline (147.951 us; speedup 1.0000x reference)
//
#include <hip/hip_runtime.h>

// Conv2D 3x3 stride-1 pad-1, C_IN=C_OUT=16, H=W=1024, fp32 in/out.
// Implicit-GEMM on bf16 MFMA: M=c_out(16), N=pixels, K=(kh,cin) packed.
// Per block: stage 18x66x16 halo tile to LDS as bf16, then 4 waves each
// compute a 16-wide column group over 16 rows with mfma_f32_16x16x32_bf16.

#define HH 1024
#define WW 1024
#define CIN 16
#define COUT 16
#define TW 64
#define TH 16
#define LROWS (TH + 2)
#define LCOLS (TW + 2)
#define PIX 16  // shorts (bf16) per pixel in LDS; 32B stride keeps b128 reads 16B-aligned

typedef short v8s __attribute__((ext_vector_type(8)));
typedef float v4f __attribute__((ext_vector_type(4)));

__device__ __forceinline__ unsigned short f32_bf16(float f) {
    union { float f; unsigned int u; } v;
    v.f = f;
    unsigned int u = v.u;
    u += 0x7fffu + ((u >> 16) & 1u);  // round-to-nearest-even
    return (unsigned short)(u >> 16);
}

__global__ __launch_bounds__(256, 4)
void conv3x3_mfma(const float* __restrict__ x,
                  const float* __restrict__ wgt,
                  const float* __restrict__ bias,
                  float* __restrict__ out) {
    __shared__ __align__(16) unsigned short sm[LROWS * LCOLS * PIX];

    const int tid = threadIdx.x;
    const int h0 = blockIdx.y * TH;
    const int w0 = blockIdx.x * TW;

    // ---- stage halo tile: fp32 global -> bf16 LDS, [row][col][cin] ----
    const int E = LROWS * LCOLS * CIN;  // 19008
    for (int e = tid; e < E; e += 256) {
        int c = e % LCOLS;          // col fastest -> coalesced global reads
        int t = e / LCOLS;
        int r = t % LROWS;
        int cin = t / LROWS;
        int gh = h0 - 1 + r;
        int gw = w0 - 1 + c;
        float v = 0.0f;
        if ((unsigned)gh < (unsigned)HH && (unsigned)gw < (unsigned)WW)
            v = x[cin * (HH * WW) + gh * WW + gw];
        sm[(r * LCOLS + c) * PIX + cin] = f32_bf16(v);
    }

    const int lane = tid & 63;
    const int wave = tid >> 6;
    const int m = lane & 15;       // c_out row of A / column n of B&D
    const int q = lane >> 4;       // quad
    const int qh = q >> 1;         // kh covered by MFMA #1 for this quad (0 or 1)
    const int qc = (q & 1) * 8;    // cin offset within MFMA #1

    // ---- A fragments (weights), preloaded to VGPRs ----
    // MFMA #1: k = kh*16 + cin, kh in {0,1};  MFMA #2: k<16 -> kh=2, else 0.
    v8s a1[3], a2[3];
    for (int kw = 0; kw < 3; ++kw) {
        for (int j = 0; j < 8; ++j) {
            a1[kw][j] = (short)f32_bf16(wgt[((m * CIN + (qc + j)) * 3 + qh) * 3 + kw]);
            short t2 = 0;
            if (q < 2)
                t2 = (short)f32_bf16(wgt[((m * CIN + (q * 8 + j)) * 3 + 2) * 3 + kw]);
            a2[kw][j] = t2;
        }
    }
    float bl[4];
    #pragma unroll
    for (int i = 0; i < 4; ++i) bl[i] = bias[q * 4 + i];

    __syncthreads();

    // ---- compute: wave = column group (16 pixels wide), loop 16 rows ----
    const int colbase = wave * 16 + m;  // LDS col of pixel (w0 + wave*16 + n) is colbase+1-1+kw
    for (int r = 0; r < TH; ++r) {
        v4f accA = {0.f, 0.f, 0.f, 0.f};
        v4f accB = {0.f, 0.f, 0.f, 0.f};
        #pragma unroll
        for (int kw = 0; kw < 3; ++kw) {
            const int col = colbase + kw;  // sm col 0 == global w0-1
            v8s b1 = *(const v8s*)&sm[((r + qh) * LCOLS + col) * PIX + qc];
            accA = __builtin_amdgcn_mfma_f32_16x16x32_bf16(a1[kw], b1, accA, 0, 0, 0);
            v8s b2 = {0, 0, 0, 0, 0, 0, 0, 0};
            if (q < 2)
                b2 = *(const v8s*)&sm[((r + 2) * LCOLS + col) * PIX + q * 8];
            accB = __builtin_amdgcn_mfma_f32_16x16x32_bf16(a2[kw], b2, accB, 0, 0, 0);
        }
        const int h = h0 + r;
        float* op = out + h * WW + (w0 + colbase);
        #pragma unroll
        for (int i = 0; i < 4; ++i) {
            // D row = q*4 + i = c_out plane
            op[(q * 4 + i) * (HH * WW)] = accA[i] + accB[i] + bl[i];
        }
    }
}

extern "C" void kernel_launch(void* const* d_in, const int* in_sizes, int n_in,
                              void* d_out, int out_size, void* d_ws, size_t ws_size,
                              hipStream_t stream) {
    const float* x = (const float*)d_in[0];
    const float* w = (const float*)d_in[1];
    const float* b = (const float*)d_in[2];
    float* out = (float*)d_out;
    dim3 grid(WW / TW, HH / TH);
    conv3x3_mfma<<<grid, dim3(256), 0, stream>>>(x, w, b, out);
}